// Round 6
// baseline (982.864 us; speedup 1.0000x reference)
//
#include <hip/hip_runtime.h>
#include <hip/hip_fp16.h>

#define NROWS   16384
#define NCOL    4096
#define NSTAGES 12
#define NPAIRS  2048
#define ROWS_PB 16
#define TILES   8   // 2 rows per tile

// ---- LDS bank swizzles for the two exchanges (validated R1-R5) ----
__device__ __forceinline__ int swz1(int W) {
  return W ^ (((W >> 8) & 1) << 4) ^ (((W >> 5) & 3) << 2);
}
__device__ __forceinline__ int swz2(int W) {
  return W ^ (((W >> 7) & 1) << 4) ^ (((W >> 5) & 3) << 2);
}

// pair index needed by lane t, stage s, sub-pair p (matches butterfly layouts)
__device__ __forceinline__ int pair_idx(int s, int t, int p) {
  int thi = t >> 4, tlo = t & 15;
  return (s < 4) ? (t * 8 + p) : (s < 8) ? (thi * 128 + p * 16 + tlo) : (p * 256 + t);
}

// Permuted table: tab4[(s*4+k)*256 + t] = {cos,sin,cos,sin} for p=2k,2k+1.
__global__ void cs_table_kernel(const float* __restrict__ ang, float4* __restrict__ tab4) {
  int tid = blockIdx.x * blockDim.x + threadIdx.x;
  if (tid >= NSTAGES * 4 * 256) return;
  int s = tid >> 10;
  int rem = tid & 1023;
  int k = rem >> 8;
  int t = rem & 255;
  float c[2], sn[2];
#pragma unroll
  for (int e = 0; e < 2; ++e) {
    int pr = pair_idx(s, t, 2 * k + e);
    float sv, cv;
    sincosf(ang[s * NPAIRS + pr], &sv, &cv);
    c[e] = cv; sn[e] = sv;
  }
  tab4[(s * 4 + k) * 256 + t] = make_float4(c[0], sn[0], c[1], sn[1]);
}

// wave-lockstep LDS fence (validated R5): lgkmcnt(0) + scheduling pin
__device__ __forceinline__ void wave_lds_fence() {
  asm volatile("s_waitcnt lgkmcnt(0)" ::: "memory");
  __builtin_amdgcn_sched_barrier(0);
}

// block barrier WITHOUT vmcnt drain (raw s_barrier keeps prefetch loads in
// flight; __syncthreads would emit s_waitcnt vmcnt(0) and kill the pipeline)
__device__ __forceinline__ void block_barrier_lgkm() {
  asm volatile("s_waitcnt lgkmcnt(0)" ::: "memory");
  __builtin_amdgcn_sched_barrier(0);
  __builtin_amdgcn_s_barrier();
  __builtin_amdgcn_sched_barrier(0);
}

template <bool TAB>
__global__ __launch_bounds__(256, 2) void butterfly_kernel(
    const float* __restrict__ x, const float4* __restrict__ tab4,
    const float* __restrict__ ang, float* __restrict__ out) {
  __shared__ __align__(16) float lds[2][NCOL];

  const int t   = threadIdx.x;
  const int w   = t >> 6;   // wave id
  const int l   = t & 63;   // lane id
  const int thi = t >> 4;
  const int tlo = t & 15;
  const size_t row0 = (size_t)blockIdx.x * ROWS_PB;

  // ---- prefetch tile 0 (wave-local chunks, lane-contiguous) ----
  float4 st[2][4];
#pragma unroll
  for (int r = 0; r < 2; ++r) {
    const float4* row4 = reinterpret_cast<const float4*>(x + (row0 + r) * NCOL);
#pragma unroll
    for (int k = 0; k < 4; ++k)
      st[r][k] = row4[256 * w + 64 * k + l];
  }

  // ---- rotation table -> registers, packed fp16x2 (c,s) per pair.
  //      96 regs; zero table VMEM traffic in the tile loop. ----
  __half2 tab[NSTAGES * 8];
  if constexpr (TAB) {
#pragma unroll
    for (int s = 0; s < NSTAGES; ++s)
#pragma unroll
      for (int k = 0; k < 4; ++k) {
        float4 q = tab4[(s * 4 + k) * 256 + t];
        tab[s * 8 + 2 * k]     = __floats2half2_rn(q.x, q.y);
        tab[s * 8 + 2 * k + 1] = __floats2half2_rn(q.z, q.w);
      }
  } else {
#pragma unroll
    for (int s = 0; s < NSTAGES; ++s)
#pragma unroll
      for (int p = 0; p < 8; ++p) {
        float sv, cv;
        sincosf(ang[s * NPAIRS + pair_idx(s, t, p)], &sv, &cv);
        tab[s * 8 + p] = __floats2half2_rn(cv, sv);
      }
  }

  float v[2][16];

#pragma unroll
  for (int tile = 0; tile < TILES; ++tile) {
    // ---- stage current tile into LDS (swizzled sigma(c)=c^((c>>3)&7));
    //      compiler inserts the vmcnt wait on st use ----
#pragma unroll
    for (int r = 0; r < 2; ++r)
#pragma unroll
      for (int k = 0; k < 4; ++k) {
        const int c  = 256 * w + 64 * k + l;
        const int cs = c ^ ((c >> 3) & 7);
        *reinterpret_cast<float4*>(&lds[r][cs * 4]) = st[r][k];
      }
    wave_lds_fence();   // writes visible to own wave; st regs consumed

    // ---- issue next tile's loads now: ~900cy HBM latency hides under compute ----
    if (tile + 1 < TILES) {
#pragma unroll
      for (int r = 0; r < 2; ++r) {
        const float4* row4 = reinterpret_cast<const float4*>(
            x + (row0 + 2 * (tile + 1) + r) * NCOL);
#pragma unroll
        for (int k = 0; k < 4; ++k)
          st[r][k] = row4[256 * w + 64 * k + l];
      }
    }

    // ---- phase-1 fragment read (own wave quarter) ----
#pragma unroll
    for (int r = 0; r < 2; ++r)
#pragma unroll
      for (int k = 0; k < 4; ++k) {
        int ba = (t * 64 + k * 16) ^ (((t >> 1) & 7) << 4);
        float4 q = *reinterpret_cast<const float4*>(
            reinterpret_cast<const char*>(&lds[r][0]) + ba);
        v[r][4 * k + 0] = q.x; v[r][4 * k + 1] = q.y;
        v[r][4 * k + 2] = q.z; v[r][4 * k + 3] = q.w;
      }

    // ---- phase 1: stages 0..3 ----
#pragma unroll
    for (int s = 0; s < 4; ++s) {
      const int d = 1 << s;
#pragma unroll
      for (int p = 0; p < 8; ++p) {
        float2 A = __half22float2(tab[s * 8 + p]);
        const int j0 = ((p >> s) << (s + 1)) | (p & (d - 1));
        const int j1 = j0 + d;
#pragma unroll
        for (int r = 0; r < 2; ++r) {
          float v0 = v[r][j0], v1 = v[r][j1];
          v[r][j0] = A.x * v0 - A.y * v1;
          v[r][j1] = A.y * v0 + A.x * v1;
        }
      }
    }

    // ---- exchange 1 (wave-local: stays in quarter n[11:10]=w) ----
#pragma unroll
    for (int r = 0; r < 2; ++r)
#pragma unroll
      for (int j = 0; j < 16; ++j)
        lds[r][swz1(thi * 256 + j * 16 + tlo)] = v[r][j];
    wave_lds_fence();
#pragma unroll
    for (int r = 0; r < 2; ++r)
#pragma unroll
      for (int k = 0; k < 4; ++k) {
        float4 q = *reinterpret_cast<const float4*>(
            &lds[r][swz1(thi * 256 + tlo * 16 + 4 * k)]);
        v[r][4 * k + 0] = q.x; v[r][4 * k + 1] = q.y;
        v[r][4 * k + 2] = q.z; v[r][4 * k + 3] = q.w;
      }

    // ---- phase 2: stages 4..7 ----
#pragma unroll
    for (int s = 0; s < 4; ++s) {
      const int d = 1 << s;
#pragma unroll
      for (int p = 0; p < 8; ++p) {
        float2 A = __half22float2(tab[(s + 4) * 8 + p]);
        const int j0 = ((p >> s) << (s + 1)) | (p & (d - 1));
        const int j1 = j0 + d;
#pragma unroll
        for (int r = 0; r < 2; ++r) {
          float v0 = v[r][j0], v1 = v[r][j1];
          v[r][j0] = A.x * v0 - A.y * v1;
          v[r][j1] = A.y * v0 + A.x * v1;
        }
      }
    }

    // ---- exchange 2 (exch2-writes are cross-wave: the only block syncs) ----
    block_barrier_lgkm();   // all waves done reading their quarters
#pragma unroll
    for (int r = 0; r < 2; ++r)
#pragma unroll
      for (int j = 0; j < 16; ++j)
        lds[r][swz2(j * 256 + tlo * 16 + thi)] = v[r][j];
    block_barrier_lgkm();   // cross-writes drained + visible
#pragma unroll
    for (int r = 0; r < 2; ++r)
#pragma unroll
      for (int k = 0; k < 4; ++k) {
        float4 q = *reinterpret_cast<const float4*>(
            &lds[r][swz2(thi * 256 + tlo * 16 + 4 * k)]);
        v[r][4 * k + 0] = q.x; v[r][4 * k + 1] = q.y;
        v[r][4 * k + 2] = q.z; v[r][4 * k + 3] = q.w;
      }
    // after this point my quarter is only ever read by me -> next tile's
    // staging write needs no further barrier.

    // ---- phase 3: stages 8..11 ----
#pragma unroll
    for (int s = 0; s < 4; ++s) {
      const int d = 1 << s;
#pragma unroll
      for (int p = 0; p < 8; ++p) {
        float2 A = __half22float2(tab[(s + 8) * 8 + p]);
        const int j0 = ((p >> s) << (s + 1)) | (p & (d - 1));
        const int j1 = j0 + d;
#pragma unroll
        for (int r = 0; r < 2; ++r) {
          float v0 = v[r][j0], v1 = v[r][j1];
          v[r][j0] = A.x * v0 - A.y * v1;
          v[r][j1] = A.y * v0 + A.x * v1;
        }
      }
    }

    // ---- store (elem i*256 + t: lanes contiguous, coalesced) ----
#pragma unroll
    for (int r = 0; r < 2; ++r) {
      float* orow = out + (row0 + 2 * tile + r) * NCOL;
#pragma unroll
      for (int i = 0; i < 16; ++i)
        orow[i * 256 + t] = v[r][i];
    }
  }
}

extern "C" void kernel_launch(void* const* d_in, const int* in_sizes, int n_in,
                              void* d_out, int out_size, void* d_ws, size_t ws_size,
                              hipStream_t stream) {
  const float* x   = (const float*)d_in[0];
  const float* ang = (const float*)d_in[1];
  float* out       = (float*)d_out;

  const size_t tab_bytes = (size_t)NSTAGES * 4 * 256 * sizeof(float4);  // 192 KB
  const int nblocks = NROWS / ROWS_PB;  // 1024

  if (ws_size >= tab_bytes) {
    float4* tab4 = (float4*)d_ws;
    cs_table_kernel<<<(NSTAGES * 4 * 256 + 255) / 256, 256, 0, stream>>>(ang, tab4);
    butterfly_kernel<true><<<nblocks, 256, 0, stream>>>(x, tab4, nullptr, out);
  } else {
    butterfly_kernel<false><<<nblocks, 256, 0, stream>>>(x, nullptr, ang, out);
  }
}

// Round 7
// 331.626 us; speedup vs baseline: 2.9638x; 2.9638x over previous
//
#include <hip/hip_runtime.h>
#include <hip/hip_fp16.h>

#define NROWS   16384
#define NCOL    4096
#define NSTAGES 12
#define NPAIRS  2048
#define ROWS_PB 16
#define TILES   8   // 2 rows per tile

// ---- LDS bank swizzles for the two exchanges (validated R1-R6) ----
__device__ __forceinline__ int swz1(int W) {
  return W ^ (((W >> 8) & 1) << 4) ^ (((W >> 5) & 3) << 2);
}
__device__ __forceinline__ int swz2(int W) {
  return W ^ (((W >> 7) & 1) << 4) ^ (((W >> 5) & 3) << 2);
}

// pair index needed by lane t, stage s, sub-pair p (matches butterfly layouts)
__device__ __forceinline__ int pair_idx(int s, int t, int p) {
  int thi = t >> 4, tlo = t & 15;
  return (s < 4) ? (t * 8 + p) : (s < 8) ? (thi * 128 + p * 16 + tlo) : (p * 256 + t);
}

// fp16 packed table: tabq[(s*2+h)*256 + t] = uint4 of 4 half2 {cos,sin},
// pairs p = 4h..4h+3 for lane t, stage s.  Validated fp16 accuracy in R6
// (absmax 0.031 < 0.1175).
__global__ void cs_table_kernel(const float* __restrict__ ang, uint4* __restrict__ tabq) {
  int tid = blockIdx.x * blockDim.x + threadIdx.x;
  if (tid >= NSTAGES * 2 * 256) return;
  int s = tid >> 9;
  int h = (tid >> 8) & 1;
  int t = tid & 255;
  unsigned r[4];
#pragma unroll
  for (int e = 0; e < 4; ++e) {
    int pr = pair_idx(s, t, 4 * h + e);
    float sv, cv;
    sincosf(ang[s * NPAIRS + pr], &sv, &cv);
    __half2 hh = __floats2half2_rn(cv, sv);
    r[e] = *reinterpret_cast<unsigned*>(&hh);
  }
  tabq[tid] = make_uint4(r[0], r[1], r[2], r[3]);
}

__device__ __forceinline__ float2 h2f(unsigned u) {
  __half2 h = *reinterpret_cast<__half2*>(&u);
  return __half22float2(h);
}

// wave-lockstep LDS fence (validated R5/R6)
__device__ __forceinline__ void wave_lds_fence() {
  asm volatile("s_waitcnt lgkmcnt(0)" ::: "memory");
  __builtin_amdgcn_sched_barrier(0);
}

// block barrier WITHOUT vmcnt drain (keeps prefetch loads in flight)
__device__ __forceinline__ void block_barrier_lgkm() {
  asm volatile("s_waitcnt lgkmcnt(0)" ::: "memory");
  __builtin_amdgcn_sched_barrier(0);
  __builtin_amdgcn_s_barrier();
  __builtin_amdgcn_sched_barrier(0);
}

// One 4-stage phase; table values loaded per-stage with one-stage-ahead
// prefetch (all-SSA, static indexing -> no scratch).
template <int BASE, bool TAB>
__device__ __forceinline__ void rot_phase(const uint4* __restrict__ tabq,
                                          const float* __restrict__ ang,
                                          int t, float v[2][16]) {
  uint4 qa, qb;
  if constexpr (TAB) {
    qa = tabq[(BASE * 2 + 0) * 256 + t];
    qb = tabq[(BASE * 2 + 1) * 256 + t];
  }
#pragma unroll
  for (int ss = 0; ss < 4; ++ss) {
    uint4 na = qa, nb = qb;
    if constexpr (TAB) {
      if (ss < 3) {
        na = tabq[((BASE + ss + 1) * 2 + 0) * 256 + t];
        nb = tabq[((BASE + ss + 1) * 2 + 1) * 256 + t];
      }
    }
    const int d = 1 << ss;
    const unsigned aw[8] = {qa.x, qa.y, qa.z, qa.w, qb.x, qb.y, qb.z, qb.w};
#pragma unroll
    for (int p = 0; p < 8; ++p) {
      float2 A;
      if constexpr (TAB) {
        A = h2f(aw[p]);
      } else {
        float sv, cv;
        sincosf(ang[(BASE + ss) * NPAIRS + pair_idx(BASE + ss, t, p)], &sv, &cv);
        A = make_float2(cv, sv);
      }
      const int j0 = ((p >> ss) << (ss + 1)) | (p & (d - 1));
      const int j1 = j0 + d;
#pragma unroll
      for (int r = 0; r < 2; ++r) {
        float v0 = v[r][j0], v1 = v[r][j1];
        v[r][j0] = A.x * v0 - A.y * v1;
        v[r][j1] = A.y * v0 + A.x * v1;
      }
    }
    qa = na; qb = nb;
  }
}

template <bool TAB>
__global__ __launch_bounds__(256, 3) void butterfly_kernel(
    const float* __restrict__ x, const uint4* __restrict__ tabq,
    const float* __restrict__ ang, float* __restrict__ out) {
  __shared__ __align__(16) float lds[2][NCOL];

  const int t   = threadIdx.x;
  const int w   = t >> 6;   // wave id
  const int l   = t & 63;   // lane id
  const int thi = t >> 4;
  const int tlo = t & 15;
  const size_t row0 = (size_t)blockIdx.x * ROWS_PB;

  // ---- prefetch tile 0 (wave-local chunks, lane-contiguous) ----
  float4 st[2][4];
#pragma unroll
  for (int r = 0; r < 2; ++r) {
    const float4* row4 = reinterpret_cast<const float4*>(x + (row0 + r) * NCOL);
#pragma unroll
    for (int k = 0; k < 4; ++k)
      st[r][k] = row4[256 * w + 64 * k + l];
  }

  float v[2][16];

#pragma unroll 1
  for (int tile = 0; tile < TILES; ++tile) {
    // ---- stage current tile into LDS (swizzled sigma(c)=c^((c>>3)&7)) ----
#pragma unroll
    for (int r = 0; r < 2; ++r)
#pragma unroll
      for (int k = 0; k < 4; ++k) {
        const int c  = 256 * w + 64 * k + l;
        const int cs = c ^ ((c >> 3) & 7);
        *reinterpret_cast<float4*>(&lds[r][cs * 4]) = st[r][k];
      }
    wave_lds_fence();   // writes visible to own wave; st regs consumed

    // ---- issue next tile's loads now: HBM latency hides under compute ----
    if (tile + 1 < TILES) {
#pragma unroll
      for (int r = 0; r < 2; ++r) {
        const float4* row4 = reinterpret_cast<const float4*>(
            x + (row0 + 2 * (tile + 1) + r) * NCOL);
#pragma unroll
        for (int k = 0; k < 4; ++k)
          st[r][k] = row4[256 * w + 64 * k + l];
      }
    }

    // ---- phase-1 fragment read (own wave quarter) ----
#pragma unroll
    for (int r = 0; r < 2; ++r)
#pragma unroll
      for (int k = 0; k < 4; ++k) {
        int ba = (t * 64 + k * 16) ^ (((t >> 1) & 7) << 4);
        float4 q = *reinterpret_cast<const float4*>(
            reinterpret_cast<const char*>(&lds[r][0]) + ba);
        v[r][4 * k + 0] = q.x; v[r][4 * k + 1] = q.y;
        v[r][4 * k + 2] = q.z; v[r][4 * k + 3] = q.w;
      }

    // ---- phase 1: stages 0..3 ----
    rot_phase<0, TAB>(tabq, ang, t, v);

    // ---- exchange 1 (wave-local: stays in quarter n[11:10]=w) ----
#pragma unroll
    for (int r = 0; r < 2; ++r)
#pragma unroll
      for (int j = 0; j < 16; ++j)
        lds[r][swz1(thi * 256 + j * 16 + tlo)] = v[r][j];
    wave_lds_fence();
#pragma unroll
    for (int r = 0; r < 2; ++r)
#pragma unroll
      for (int k = 0; k < 4; ++k) {
        float4 q = *reinterpret_cast<const float4*>(
            &lds[r][swz1(thi * 256 + tlo * 16 + 4 * k)]);
        v[r][4 * k + 0] = q.x; v[r][4 * k + 1] = q.y;
        v[r][4 * k + 2] = q.z; v[r][4 * k + 3] = q.w;
      }

    // ---- phase 2: stages 4..7 ----
    rot_phase<4, TAB>(tabq, ang, t, v);

    // ---- exchange 2 (cross-wave: the only block syncs) ----
    block_barrier_lgkm();
#pragma unroll
    for (int r = 0; r < 2; ++r)
#pragma unroll
      for (int j = 0; j < 16; ++j)
        lds[r][swz2(j * 256 + tlo * 16 + thi)] = v[r][j];
    block_barrier_lgkm();
#pragma unroll
    for (int r = 0; r < 2; ++r)
#pragma unroll
      for (int k = 0; k < 4; ++k) {
        float4 q = *reinterpret_cast<const float4*>(
            &lds[r][swz2(thi * 256 + tlo * 16 + 4 * k)]);
        v[r][4 * k + 0] = q.x; v[r][4 * k + 1] = q.y;
        v[r][4 * k + 2] = q.z; v[r][4 * k + 3] = q.w;
      }

    // ---- phase 3: stages 8..11 ----
    rot_phase<8, TAB>(tabq, ang, t, v);

    // ---- store (elem i*256 + t: lanes contiguous, coalesced) ----
#pragma unroll
    for (int r = 0; r < 2; ++r) {
      float* orow = out + (row0 + 2 * tile + r) * NCOL;
#pragma unroll
      for (int i = 0; i < 16; ++i)
        orow[i * 256 + t] = v[r][i];
    }
  }
}

extern "C" void kernel_launch(void* const* d_in, const int* in_sizes, int n_in,
                              void* d_out, int out_size, void* d_ws, size_t ws_size,
                              hipStream_t stream) {
  const float* x   = (const float*)d_in[0];
  const float* ang = (const float*)d_in[1];
  float* out       = (float*)d_out;

  const size_t tab_bytes = (size_t)NSTAGES * 2 * 256 * sizeof(uint4);  // 96 KB
  const int nblocks = NROWS / ROWS_PB;  // 1024

  if (ws_size >= tab_bytes) {
    uint4* tabq = (uint4*)d_ws;
    cs_table_kernel<<<(NSTAGES * 2 * 256 + 255) / 256, 256, 0, stream>>>(ang, tabq);
    butterfly_kernel<true><<<nblocks, 256, 0, stream>>>(x, tabq, nullptr, out);
  } else {
    butterfly_kernel<false><<<nblocks, 256, 0, stream>>>(x, nullptr, ang, out);
  }
}

// Round 8
// 118.922 us; speedup vs baseline: 8.2648x; 2.7886x over previous
//
#include <hip/hip_runtime.h>
#include <hip/hip_fp16.h>

#define NROWS   16384
#define NCOL    4096
#define NSTAGES 12
#define NPAIRS  2048
#define RPB     2   // rows per block (32 KB LDS) — R3/R5 proven shape

// ---- LDS bank swizzles for the two exchanges (validated R1-R7) ----
__device__ __forceinline__ int swz1(int W) {
  return W ^ (((W >> 8) & 1) << 4) ^ (((W >> 5) & 3) << 2);
}
__device__ __forceinline__ int swz2(int W) {
  return W ^ (((W >> 7) & 1) << 4) ^ (((W >> 5) & 3) << 2);
}

// pair index needed by lane t, stage s, sub-pair p (matches butterfly layouts)
__device__ __forceinline__ int pair_idx(int s, int t, int p) {
  int thi = t >> 4, tlo = t & 15;
  return (s < 4) ? (t * 8 + p) : (s < 8) ? (thi * 128 + p * 16 + tlo) : (p * 256 + t);
}

// fp16 packed table: tabq[(s*2+h)*256 + t] = uint4 of 4 half2 {cos,sin},
// pairs p = 4h..4h+3 for lane t, stage s. fp16 accuracy validated R6/R7
// (absmax 0.031 < 0.1175 threshold).
__global__ void cs_table_kernel(const float* __restrict__ ang, uint4* __restrict__ tabq) {
  int tid = blockIdx.x * blockDim.x + threadIdx.x;
  if (tid >= NSTAGES * 2 * 256) return;
  int s = tid >> 9;
  int h = (tid >> 8) & 1;
  int t = tid & 255;
  unsigned r[4];
#pragma unroll
  for (int e = 0; e < 4; ++e) {
    int pr = pair_idx(s, t, 4 * h + e);
    float sv, cv;
    sincosf(ang[s * NPAIRS + pr], &sv, &cv);
    __half2 hh = __floats2half2_rn(cv, sv);
    r[e] = *reinterpret_cast<unsigned*>(&hh);
  }
  tabq[tid] = make_uint4(r[0], r[1], r[2], r[3]);
}

__device__ __forceinline__ float2 h2f(unsigned u) {
  __half2 h = *reinterpret_cast<__half2*>(&u);
  return __half22float2(h);
}

// load one stage's 8 rotation pairs for lane t (2 dwordx4 at fp16 vs 4 at f32)
template <bool TAB>
__device__ __forceinline__ void load_A(int s, int t, const uint4* __restrict__ tabq,
                                       const float* __restrict__ ang, float2* A) {
  if constexpr (TAB) {
    uint4 qa = tabq[(s * 2 + 0) * 256 + t];
    uint4 qb = tabq[(s * 2 + 1) * 256 + t];
    A[0] = h2f(qa.x); A[1] = h2f(qa.y); A[2] = h2f(qa.z); A[3] = h2f(qa.w);
    A[4] = h2f(qb.x); A[5] = h2f(qb.y); A[6] = h2f(qb.z); A[7] = h2f(qb.w);
  } else {
#pragma unroll
    for (int p = 0; p < 8; ++p) {
      float sv, cv;
      sincosf(ang[s * NPAIRS + pair_idx(s, t, p)], &sv, &cv);
      A[p] = make_float2(cv, sv);
    }
  }
}

// wave-lockstep LDS fence (validated R5): lgkmcnt(0) + scheduling pin
__device__ __forceinline__ void wave_lds_fence() {
  asm volatile("s_waitcnt lgkmcnt(0)" ::: "memory");
  __builtin_amdgcn_sched_barrier(0);
}

template <bool TAB>
__global__ __launch_bounds__(256, 5) void butterfly_kernel(
    const float* __restrict__ x, const uint4* __restrict__ tabq,
    const float* __restrict__ ang, float* __restrict__ out) {
  __shared__ __align__(16) float lds[RPB][NCOL];

  const int t   = threadIdx.x;
  const int w   = t >> 6;   // wave id
  const int l   = t & 63;   // lane id
  const int thi = t >> 4;
  const int tlo = t & 15;
  const size_t row0 = (size_t)blockIdx.x * RPB;

  // ---- WAVE-LOCAL staging: wave w loads exactly the chunks its threads read
  //      in phase 1; ds_write to swizzled chunk sigma(c)=c^((c>>3)&7). ----
  float4 st[RPB][4];
#pragma unroll
  for (int r = 0; r < RPB; ++r) {
    const float4* row4 = reinterpret_cast<const float4*>(x + (row0 + r) * NCOL);
#pragma unroll
    for (int k = 0; k < 4; ++k)
      st[r][k] = row4[256 * w + 64 * k + l];
  }
#pragma unroll
  for (int r = 0; r < RPB; ++r) {
#pragma unroll
    for (int k = 0; k < 4; ++k) {
      const int c  = 256 * w + 64 * k + l;
      const int cs = c ^ ((c >> 3) & 7);
      *reinterpret_cast<float4*>(&lds[r][cs * 4]) = st[r][k];
    }
  }
  wave_lds_fence();

  // ---- phase-1 fragment read (wave-local): thread t gets words [t*16, t*16+16) ----
  float v[RPB][16];
#pragma unroll
  for (int r = 0; r < RPB; ++r) {
#pragma unroll
    for (int k = 0; k < 4; ++k) {
      int ba = (t * 64 + k * 16) ^ (((t >> 1) & 7) << 4);  // swizzled byte addr
      float4 q = *reinterpret_cast<const float4*>(
          reinterpret_cast<const char*>(&lds[r][0]) + ba);
      v[r][4 * k + 0] = q.x; v[r][4 * k + 1] = q.y;
      v[r][4 * k + 2] = q.z; v[r][4 * k + 3] = q.w;
    }
  }

  float2 A[8];

  // ---- phase 1: stages 0..3 (bits 0-3 thread-local) ----
#pragma unroll
  for (int s = 0; s < 4; ++s) {
    load_A<TAB>(s, t, tabq, ang, A);
    const int qq = s & 3, d = 1 << qq;
#pragma unroll
    for (int r = 0; r < RPB; ++r) {
#pragma unroll
      for (int p = 0; p < 8; ++p) {
        const int j0 = ((p >> qq) << (qq + 1)) | (p & (d - 1));
        const int j1 = j0 + d;
        float v0 = v[r][j0], v1 = v[r][j1];
        v[r][j0] = A[p].x * v0 - A[p].y * v1;
        v[r][j1] = A[p].y * v0 + A[p].x * v1;
      }
    }
  }

  // ---- exchange 1 (WAVE-LOCAL: both sides stay in quarter n[11:10]=w) ----
#pragma unroll
  for (int r = 0; r < RPB; ++r)
#pragma unroll
    for (int j = 0; j < 16; ++j)
      lds[r][swz1(thi * 256 + j * 16 + tlo)] = v[r][j];
  wave_lds_fence();

#pragma unroll
  for (int r = 0; r < RPB; ++r) {
#pragma unroll
    for (int k = 0; k < 4; ++k) {
      float4 q = *reinterpret_cast<const float4*>(&lds[r][swz1(thi * 256 + tlo * 16 + 4 * k)]);
      v[r][4 * k + 0] = q.x; v[r][4 * k + 1] = q.y;
      v[r][4 * k + 2] = q.z; v[r][4 * k + 3] = q.w;
    }
  }

  // ---- phase 2: stages 4..7 (bits 4-7 thread-local) ----
#pragma unroll
  for (int s = 4; s < 8; ++s) {
    load_A<TAB>(s, t, tabq, ang, A);
    const int qq = s & 3, d = 1 << qq;
#pragma unroll
    for (int r = 0; r < RPB; ++r) {
#pragma unroll
      for (int p = 0; p < 8; ++p) {
        const int j0 = ((p >> qq) << (qq + 1)) | (p & (d - 1));
        const int j1 = j0 + d;
        float v0 = v[r][j0], v1 = v[r][j1];
        v[r][j0] = A[p].x * v0 - A[p].y * v1;
        v[r][j1] = A[p].y * v0 + A[p].x * v1;
      }
    }
  }

  // ---- exchange 2 (cross-wave: the only block barriers in the kernel) ----
  __syncthreads();
#pragma unroll
  for (int r = 0; r < RPB; ++r)
#pragma unroll
    for (int j = 0; j < 16; ++j)
      lds[r][swz2(j * 256 + tlo * 16 + thi)] = v[r][j];
  __syncthreads();

#pragma unroll
  for (int r = 0; r < RPB; ++r) {
#pragma unroll
    for (int k = 0; k < 4; ++k) {
      float4 q = *reinterpret_cast<const float4*>(&lds[r][swz2(thi * 256 + tlo * 16 + 4 * k)]);
      v[r][4 * k + 0] = q.x; v[r][4 * k + 1] = q.y;
      v[r][4 * k + 2] = q.z; v[r][4 * k + 3] = q.w;
    }
  }

  // ---- phase 3: stages 8..11 (bits 8-11 thread-local) ----
#pragma unroll
  for (int s = 8; s < 12; ++s) {
    load_A<TAB>(s, t, tabq, ang, A);
    const int qq = s & 3, d = 1 << qq;
#pragma unroll
    for (int r = 0; r < RPB; ++r) {
#pragma unroll
      for (int p = 0; p < 8; ++p) {
        const int j0 = ((p >> qq) << (qq + 1)) | (p & (d - 1));
        const int j1 = j0 + d;
        float v0 = v[r][j0], v1 = v[r][j1];
        v[r][j0] = A[p].x * v0 - A[p].y * v1;
        v[r][j1] = A[p].y * v0 + A[p].x * v1;
      }
    }
  }

  // ---- store (elem i*256 + t: lanes contiguous, coalesced) ----
#pragma unroll
  for (int r = 0; r < RPB; ++r) {
    float* orow = out + (row0 + r) * NCOL;
#pragma unroll
    for (int i = 0; i < 16; ++i)
      orow[i * 256 + t] = v[r][i];
  }
}

extern "C" void kernel_launch(void* const* d_in, const int* in_sizes, int n_in,
                              void* d_out, int out_size, void* d_ws, size_t ws_size,
                              hipStream_t stream) {
  const float* x   = (const float*)d_in[0];
  const float* ang = (const float*)d_in[1];
  float* out       = (float*)d_out;

  const size_t tab_bytes = (size_t)NSTAGES * 2 * 256 * sizeof(uint4);  // 96 KB
  const int nblocks = NROWS / RPB;  // 8192

  if (ws_size >= tab_bytes) {
    uint4* tabq = (uint4*)d_ws;
    cs_table_kernel<<<(NSTAGES * 2 * 256 + 255) / 256, 256, 0, stream>>>(ang, tabq);
    butterfly_kernel<true><<<nblocks, 256, 0, stream>>>(x, tabq, nullptr, out);
  } else {
    butterfly_kernel<false><<<nblocks, 256, 0, stream>>>(x, nullptr, ang, out);
  }
}